// Round 16
// baseline (2034.656 us; speedup 1.0000x reference)
//
#include <hip/hip_runtime.h>
#include <math.h>

#define N_NODES  100000
#define N_EDGES  3200000
#define K_IN     1433
#define NH       16
#define NO       7

#define TK       16
#define KSPLIT   9
#define CPS      10
#define RW       (CPS * TK)                   // 160
#define TILE_R   128
#define SXS      20
#define NTILEV   ((N_NODES + TILE_R - 1) / TILE_R)   // 782
#define NRBV     ((NTILEV + 3) / 4)                  // 196
#define SLOT     96

#define NBKT     256
#define BKN      391
#define SBLK     512
#define EPB      ((N_EDGES + SBLK - 1) / SBLK)

#define PREP     4                            // probe repeats

typedef float f4  __attribute__((ext_vector_type(4)));
typedef float f4u __attribute__((ext_vector_type(4), aligned(4)));

// ============== R16 PROBES: isolate X-read bandwidth by access pattern ======
// (a) exact gemm1 staging pattern: 64B granule per 4 lanes, rows 5732B apart
__global__ __launch_bounds__(256)
void k_probe_a(const float* __restrict__ X, float* __restrict__ pout) {
    const int wid = threadIdx.x >> 6;
    const int t   = threadIdx.x & 63;
    const int rb    = blockIdx.x % NRBV;
    const int split = blockIdx.x / NRBV;
    const int tile = rb * 4 + wid;
    if (tile >= NTILEV) return;
    const int base = tile * TILE_R;
    const int Lq = t & 3;
    const int Lr = t >> 2;
    const float* xp0 = X + (size_t)min(base + Lr +   0, N_NODES - 1) * K_IN + 4 * Lq;
    const float* xp1 = X + (size_t)min(base + Lr +  16, N_NODES - 1) * K_IN + 4 * Lq;
    const float* xp2 = X + (size_t)min(base + Lr +  32, N_NODES - 1) * K_IN + 4 * Lq;
    const float* xp3 = X + (size_t)min(base + Lr +  48, N_NODES - 1) * K_IN + 4 * Lq;
    const float* xp4 = X + (size_t)min(base + Lr +  64, N_NODES - 1) * K_IN + 4 * Lq;
    const float* xp5 = X + (size_t)min(base + Lr +  80, N_NODES - 1) * K_IN + 4 * Lq;
    const float* xp6 = X + (size_t)min(base + Lr +  96, N_NODES - 1) * K_IN + 4 * Lq;
    const float* xp7 = X + (size_t)min(base + Lr + 112, N_NODES - 1) * K_IN + 4 * Lq;
    f4 acc = 0.f;
    const int k0 = split * RW;
#pragma unroll 1
    for (int rep = 0; rep < PREP; ++rep) {
        asm volatile("" ::: "memory");
#pragma unroll 1
        for (int c = 0; c < CPS; ++c) {
            const int kn = k0 + c * TK;
            if (kn + TK <= K_IN) {
                acc += *(const f4u*)(xp0 + kn); acc += *(const f4u*)(xp1 + kn);
                acc += *(const f4u*)(xp2 + kn); acc += *(const f4u*)(xp3 + kn);
                acc += *(const f4u*)(xp4 + kn); acc += *(const f4u*)(xp5 + kn);
                acc += *(const f4u*)(xp6 + kn); acc += *(const f4u*)(xp7 + kn);
            } else if (Lq < 2) {
                acc += *(const f4u*)(xp0 + kn); acc += *(const f4u*)(xp1 + kn);
                acc += *(const f4u*)(xp2 + kn); acc += *(const f4u*)(xp3 + kn);
                acc += *(const f4u*)(xp4 + kn); acc += *(const f4u*)(xp5 + kn);
                acc += *(const f4u*)(xp6 + kn); acc += *(const f4u*)(xp7 + kn);
            } else if (Lq == 2) {
                acc[0] += xp0[kn] + xp1[kn] + xp2[kn] + xp3[kn]
                        + xp4[kn] + xp5[kn] + xp6[kn] + xp7[kn];
            }
        }
    }
    pout[(size_t)blockIdx.x * 256 + threadIdx.x] = acc[0]+acc[1]+acc[2]+acc[3];
}

// (b) control: flat sequential float4 stream over X
__global__ __launch_bounds__(256)
void k_probe_b(const float* __restrict__ X, float* __restrict__ pout) {
    const size_t n4 = (size_t)N_NODES * K_IN / 4;   // 35,825,000
    f4 acc = 0.f;
#pragma unroll 1
    for (int rep = 0; rep < PREP; ++rep) {
        asm volatile("" ::: "memory");
        for (size_t i = (size_t)blockIdx.x * 256 + threadIdx.x; i < n4;
             i += (size_t)gridDim.x * 256)
            acc += ((const f4u*)X)[i];
    }
    pout[(size_t)blockIdx.x * 256 + threadIdx.x] = acc[0]+acc[1]+acc[2]+acc[3];
}

// (c) candidate: 256B contiguous per row (16 lanes/row, 4 rows/instr)
__global__ __launch_bounds__(256)
void k_probe_c(const float* __restrict__ X, float* __restrict__ pout) {
    const int wid = threadIdx.x >> 6;
    const int t   = threadIdx.x & 63;
    const int wave = blockIdx.x * 4 + wid;
    if (wave * 64 >= N_NODES) return;
    const int row0 = wave * 64;
    const int Lq = t & 15;                      // 16 x 16B = 256B per row
    const int Lr = t >> 4;                      // 4 rows per instr
    f4 acc = 0.f;
#pragma unroll 1
    for (int rep = 0; rep < PREP; ++rep) {
        asm volatile("" ::: "memory");
#pragma unroll 1
        for (int sc = 0; sc < 23; ++sc) {       // 23 x 64k >= 1433
            const int kb = sc * 64 + Lq * 4;
            if (kb + 3 < K_IN) {
#pragma unroll
                for (int i = 0; i < 16; ++i) {
                    int r = min(row0 + Lr + 4 * i, N_NODES - 1);
                    acc += *(const f4u*)(X + (size_t)r * K_IN + kb);
                }
            }
        }
    }
    pout[(size_t)blockIdx.x * 256 + threadIdx.x] = acc[0]+acc[1]+acc[2]+acc[3];
}

// ---------------- B1..B5: atomic-free graph build (unchanged R13) ----------
__global__ __launch_bounds__(256)
void k_pcount(const int* __restrict__ key, int* __restrict__ partial) {
    __shared__ int lh[NBKT];
    lh[threadIdx.x] = 0;
    __syncthreads();
    const int e0 = blockIdx.x * EPB;
    const int e1 = min(e0 + EPB, N_EDGES);
    for (int i = e0 + threadIdx.x; i < e1; i += 256)
        atomicAdd(&lh[key[i] / BKN], 1);
    __syncthreads();
    partial[blockIdx.x * NBKT + threadIdx.x] = lh[threadIdx.x];
}

__global__ __launch_bounds__(256)
void k_colscan(const int* __restrict__ partial, int* __restrict__ pbase,
               int* __restrict__ btot) {
    __shared__ int s[256];
    const int b = blockIdx.x, t = threadIdx.x;
    const int v0 = partial[(2 * t)     * NBKT + b];
    const int v1 = partial[(2 * t + 1) * NBKT + b];
    const int pair = v0 + v1;
    s[t] = pair;
    __syncthreads();
    for (int o = 1; o < 256; o <<= 1) {
        int u = (t >= o) ? s[t - o] : 0;
        __syncthreads();
        s[t] += u;
        __syncthreads();
    }
    const int excl = s[t] - pair;
    pbase[(2 * t)     * NBKT + b] = excl;
    pbase[(2 * t + 1) * NBKT + b] = excl + v0;
    if (t == 255) btot[b] = s[255];
}

__global__ __launch_bounds__(256)
void k_basescan(const int* __restrict__ btd, int* __restrict__ bbd,
                const int* __restrict__ bts, int* __restrict__ bbs) {
    __shared__ int s[256];
    const int t = threadIdx.x;
    int v = btd[t];
    s[t] = v;
    __syncthreads();
    for (int o = 1; o < 256; o <<= 1) {
        int u = (t >= o) ? s[t - o] : 0;
        __syncthreads();
        s[t] += u;
        __syncthreads();
    }
    bbd[t] = s[t] - v;
    __syncthreads();
    v = bts[t];
    s[t] = v;
    __syncthreads();
    for (int o = 1; o < 256; o <<= 1) {
        int u = (t >= o) ? s[t - o] : 0;
        __syncthreads();
        s[t] += u;
        __syncthreads();
    }
    bbs[t] = s[t] - v;
}

__global__ __launch_bounds__(256)
void k_pscatter2(const int* __restrict__ src, const int* __restrict__ dst,
                 const int* __restrict__ pbase, const int* __restrict__ bbase,
                 int2* __restrict__ ebuf) {
    __shared__ int lh[NBKT];
    __shared__ int lb[NBKT];
    const int t = threadIdx.x;
    lh[t] = 0;
    lb[t] = bbase[t] + pbase[blockIdx.x * NBKT + t];
    __syncthreads();
    const int e0 = blockIdx.x * EPB;
    const int e1 = min(e0 + EPB, N_EDGES);
    for (int i = e0 + t; i < e1; i += 256) {
        int sv = src[i], dv = dst[i];
        int b = dv / BKN;
        int p = lb[b] + atomicAdd(&lh[b], 1);
        ebuf[p] = make_int2(sv, dv);
    }
}

__global__ __launch_bounds__(256)
void k_pscatter1(const int* __restrict__ src, const int* __restrict__ pbase,
                 const int* __restrict__ bbase, int* __restrict__ sbuf) {
    __shared__ int lh[NBKT];
    __shared__ int lb[NBKT];
    const int t = threadIdx.x;
    lh[t] = 0;
    lb[t] = bbase[t] + pbase[blockIdx.x * NBKT + t];
    __syncthreads();
    const int e0 = blockIdx.x * EPB;
    const int e1 = min(e0 + EPB, N_EDGES);
    for (int i = e0 + t; i < e1; i += 256) {
        int sv = src[i];
        int b = sv / BKN;
        int p = lb[b] + atomicAdd(&lh[b], 1);
        sbuf[p] = sv;
    }
}

__global__ __launch_bounds__(512)
void k_adj(const int2* __restrict__ ebuf, const int* __restrict__ bbase,
           const int* __restrict__ btot, int* __restrict__ adj,
           int* __restrict__ cnt) {
    __shared__ int cur[BKN];
    const int b = blockIdx.x;
    for (int i = threadIdx.x; i < BKN; i += 512) cur[i] = 0;
    __syncthreads();
    const int s0 = bbase[b], s1 = s0 + btot[b];
    const int nb = b * BKN;
    for (int i = s0 + threadIdx.x; i < s1; i += 512) {
        int2 e = ebuf[i];
        int p = atomicAdd(&cur[e.y - nb], 1);
        if (p < SLOT) adj[e.y * SLOT + p] = e.x;
    }
    __syncthreads();
    for (int i = threadIdx.x; i < BKN; i += 512) {
        int n = nb + i;
        if (n < N_NODES) cnt[n] = cur[i];
    }
}

__global__ __launch_bounds__(512)
void k_hist(const int* __restrict__ sbuf, const int* __restrict__ bbase,
            const int* __restrict__ btot, int* __restrict__ deg) {
    __shared__ int cur[BKN];
    const int b = blockIdx.x;
    for (int i = threadIdx.x; i < BKN; i += 512) cur[i] = 0;
    __syncthreads();
    const int s0 = bbase[b], s1 = s0 + btot[b];
    const int nb = b * BKN;
    for (int i = s0 + threadIdx.x; i < s1; i += 512)
        atomicAdd(&cur[sbuf[i] - nb], 1);
    __syncthreads();
    for (int i = threadIdx.x; i < BKN; i += 512) {
        int n = nb + i;
        if (n < N_NODES) deg[n] = cur[i];
    }
}

// ---------------- K2: gemm1 (unchanged R15 j-split) ----------
#define LOADG(KN, S0,S1,S2,S3,S4,S5,S6,S7)                               \
  { if ((KN) + TK <= K_IN) {                                             \
      S0 = *(const f4u*)(xp0 + (KN)); S1 = *(const f4u*)(xp1 + (KN));    \
      S2 = *(const f4u*)(xp2 + (KN)); S3 = *(const f4u*)(xp3 + (KN));    \
      S4 = *(const f4u*)(xp4 + (KN)); S5 = *(const f4u*)(xp5 + (KN));    \
      S6 = *(const f4u*)(xp6 + (KN)); S7 = *(const f4u*)(xp7 + (KN));    \
    } else {                                                             \
      S0=0.f;S1=0.f;S2=0.f;S3=0.f;S4=0.f;S5=0.f;S6=0.f;S7=0.f;           \
      if (Lq < 2) {                                                      \
        S0 = *(const f4u*)(xp0 + (KN)); S1 = *(const f4u*)(xp1 + (KN));  \
        S2 = *(const f4u*)(xp2 + (KN)); S3 = *(const f4u*)(xp3 + (KN));  \
        S4 = *(const f4u*)(xp4 + (KN)); S5 = *(const f4u*)(xp5 + (KN));  \
        S6 = *(const f4u*)(xp6 + (KN)); S7 = *(const f4u*)(xp7 + (KN));  \
      } else if (Lq == 2) {                                              \
        S0[0] = xp0[(KN)]; S1[0] = xp1[(KN)];                            \
        S2[0] = xp2[(KN)]; S3[0] = xp3[(KN)];                            \
        S4[0] = xp4[(KN)]; S5[0] = xp5[(KN)];                            \
        S6[0] = xp6[(KN)]; S7[0] = xp7[(KN)];                            \
      }                                                                  \
    } }

#define WRITE_SET(S0,S1,S2,S3,S4,S5,S6,S7)                               \
  { *(f4*)(xbw + 0*16*SXS) = S0; *(f4*)(xbw + 1*16*SXS) = S1;            \
    *(f4*)(xbw + 2*16*SXS) = S2; *(f4*)(xbw + 3*16*SXS) = S3;            \
    *(f4*)(xbw + 4*16*SXS) = S4; *(f4*)(xbw + 5*16*SXS) = S5;            \
    *(f4*)(xbw + 6*16*SXS) = S6; *(f4*)(xbw + 7*16*SXS) = S7; }

#define RFMA(CC)                                                         \
  { const float* wb = wjq + (CC) * (TK * NH);                            \
    _Pragma("unroll")                                                    \
    for (int g = 0; g < 4; ++g) {                                        \
      f4 x0 = *(const f4*)(xrd + 0*16*SXS + g*4);                        \
      f4 x1 = *(const f4*)(xrd + 1*16*SXS + g*4);                        \
      f4 x2 = *(const f4*)(xrd + 2*16*SXS + g*4);                        \
      f4 x3 = *(const f4*)(xrd + 3*16*SXS + g*4);                        \
      f4 x4 = *(const f4*)(xrd + 4*16*SXS + g*4);                        \
      f4 x5 = *(const f4*)(xrd + 5*16*SXS + g*4);                        \
      f4 x6 = *(const f4*)(xrd + 6*16*SXS + g*4);                        \
      f4 x7 = *(const f4*)(xrd + 7*16*SXS + g*4);                        \
      f4 w0v = *(const f4*)(wb + (g*4+0)*NH);                            \
      f4 w1v = *(const f4*)(wb + (g*4+1)*NH);                            \
      f4 w2v = *(const f4*)(wb + (g*4+2)*NH);                            \
      f4 w3v = *(const f4*)(wb + (g*4+3)*NH);                            \
      acc0 += x0[0]*w0v; acc0 += x0[1]*w1v; acc0 += x0[2]*w2v; acc0 += x0[3]*w3v; \
      acc1 += x1[0]*w0v; acc1 += x1[1]*w1v; acc1 += x1[2]*w2v; acc1 += x1[3]*w3v; \
      acc2 += x2[0]*w0v; acc2 += x2[1]*w1v; acc2 += x2[2]*w2v; acc2 += x2[3]*w3v; \
      acc3 += x3[0]*w0v; acc3 += x3[1]*w1v; acc3 += x3[2]*w2v; acc3 += x3[3]*w3v; \
      acc4 += x4[0]*w0v; acc4 += x4[1]*w1v; acc4 += x4[2]*w2v; acc4 += x4[3]*w3v; \
      acc5 += x5[0]*w0v; acc5 += x5[1]*w1v; acc5 += x5[2]*w2v; acc5 += x5[3]*w3v; \
      acc6 += x6[0]*w0v; acc6 += x6[1]*w1v; acc6 += x6[2]*w2v; acc6 += x6[3]*w3v; \
      acc7 += x7[0]*w0v; acc7 += x7[1]*w1v; acc7 += x7[2]*w2v; acc7 += x7[3]*w3v; \
    } }

__global__ __launch_bounds__(256)
void k_gemm1(const float* __restrict__ X, const float* __restrict__ W1,
             float* __restrict__ hpart) {
    __shared__ float wlds[RW * NH];
    __shared__ float sX[4][TILE_R * SXS];
    const int wid = threadIdx.x >> 6;
    const int t   = threadIdx.x & 63;
    const int rb    = blockIdx.x % NRBV;
    const int split = blockIdx.x / NRBV;

    {
        const f4* W1v = (const f4*)W1;
        const int wbase = split * RW;
#pragma unroll
        for (int r = 0; r < 3; ++r) {
            int idx = r * 256 + threadIdx.x;
            if (idx < RW * 4) {
                int krow = wbase + (idx >> 2);
                f4 wv = 0.f;
                if (krow < K_IN) wv = W1v[krow * 4 + (idx & 3)];
                ((f4*)wlds)[idx] = wv;
            }
        }
    }
    __syncthreads();

    const int tile = rb * 4 + wid;
    if (tile >= NTILEV) return;
    const int base = tile * TILE_R;
    const int Lq = t & 3;
    const int Lr = t >> 2;

    const float* xp0 = X + (size_t)min(base + Lr +   0, N_NODES - 1) * K_IN + 4 * Lq;
    const float* xp1 = X + (size_t)min(base + Lr +  16, N_NODES - 1) * K_IN + 4 * Lq;
    const float* xp2 = X + (size_t)min(base + Lr +  32, N_NODES - 1) * K_IN + 4 * Lq;
    const float* xp3 = X + (size_t)min(base + Lr +  48, N_NODES - 1) * K_IN + 4 * Lq;
    const float* xp4 = X + (size_t)min(base + Lr +  64, N_NODES - 1) * K_IN + 4 * Lq;
    const float* xp5 = X + (size_t)min(base + Lr +  80, N_NODES - 1) * K_IN + 4 * Lq;
    const float* xp6 = X + (size_t)min(base + Lr +  96, N_NODES - 1) * K_IN + 4 * Lq;
    const float* xp7 = X + (size_t)min(base + Lr + 112, N_NODES - 1) * K_IN + 4 * Lq;

    float* xbuf = sX[wid];
    float* xbw  = xbuf + Lr * SXS + 4 * Lq;
    const float* xrd = xbuf + Lr * SXS;
    const float* wjq = wlds + Lq * 4;

    f4 acc0 = 0.f, acc1 = 0.f, acc2 = 0.f, acc3 = 0.f;
    f4 acc4 = 0.f, acc5 = 0.f, acc6 = 0.f, acc7 = 0.f;

    f4 sP0, sP1, sP2, sP3, sP4, sP5, sP6, sP7;
    f4 sQ0, sQ1, sQ2, sQ3, sQ4, sQ5, sQ6, sQ7;

    const int k0 = split * RW;
    LOADG(k0, sP0, sP1, sP2, sP3, sP4, sP5, sP6, sP7)

#pragma unroll 1
    for (int j = 0; j < CPS / 2; ++j) {
        const int ke = k0 + 2 * j * TK;
        WRITE_SET(sP0, sP1, sP2, sP3, sP4, sP5, sP6, sP7)
        LOADG(ke + TK, sQ0, sQ1, sQ2, sQ3, sQ4, sQ5, sQ6, sQ7)
        __builtin_amdgcn_wave_barrier();
        RFMA(2 * j)
        __builtin_amdgcn_wave_barrier();
        WRITE_SET(sQ0, sQ1, sQ2, sQ3, sQ4, sQ5, sQ6, sQ7)
        if (j + 1 < CPS / 2) {
            LOADG(ke + 2 * TK, sP0, sP1, sP2, sP3, sP4, sP5, sP6, sP7)
        }
        __builtin_amdgcn_wave_barrier();
        RFMA(2 * j + 1)
        __builtin_amdgcn_wave_barrier();
    }

    const size_t sb = (size_t)split * N_NODES;
    float* op = hpart + (sb + base + Lr) * NH + Lq * 4;
#define STORE_ACC(I, A)                                                  \
    if (base + Lr + 16 * (I) < N_NODES)                                  \
        *(f4*)(op + (size_t)(16 * (I)) * NH) = A;
    STORE_ACC(0, acc0) STORE_ACC(1, acc1) STORE_ACC(2, acc2) STORE_ACC(3, acc3)
    STORE_ACC(4, acc4) STORE_ACC(5, acc5) STORE_ACC(6, acc6) STORE_ACC(7, acc7)
#undef STORE_ACC
}

// ---------------- K3: reduce ----------------
__global__ __launch_bounds__(256)
void k_reduce(const float* __restrict__ hpart, const int* __restrict__ deg_out,
              float* __restrict__ h) {
    int idx = blockIdx.x * 256 + threadIdx.x;
    if (idx >= N_NODES * 4) return;
    f4 a = 0.f;
#pragma unroll
    for (int s = 0; s < KSPLIT; ++s)
        a += ((const f4*)hpart)[(size_t)s * N_NODES * 4 + idx];
    float ns = rsqrtf((float)max(deg_out[idx >> 2], 1));
    ((f4*)h)[idx] = a * ns;
}

// ---------------- K4: layer1 ----------------
__global__ __launch_bounds__(256)
void k_layer1(const float* __restrict__ h, const int* __restrict__ adj,
              const int* __restrict__ cnt, const int* __restrict__ deg_out,
              const float* __restrict__ W2, const float* __restrict__ b1,
              float* __restrict__ g) {
    const int lane = threadIdx.x & 63;
    const int wid  = threadIdx.x >> 6;
    const int d    = blockIdx.x * 4 + wid;
    if (d >= N_NODES) return;
    const int j4 = lane & 3, slot = lane >> 2;
    const int start = d * SLOT;
    const int deg   = min(cnt[d], SLOT);
    const int end   = start + deg;
    f4 agg = 0.f;
    for (int p = start + slot; p < end; p += 16) {
        int s = adj[p];
        agg += ((const f4*)h)[s * 4 + j4];
    }
#pragma unroll
    for (int off = 4; off < 64; off <<= 1) {
        agg[0] += __shfl_xor(agg[0], off);
        agg[1] += __shfl_xor(agg[1], off);
        agg[2] += __shfl_xor(agg[2], off);
        agg[3] += __shfl_xor(agg[3], off);
    }
    __shared__ float st[4][NH];
    const float nd = rsqrtf((float)max(deg, 1));
    if (slot == 0) {
        f4 bb = ((const f4*)b1)[j4];
        f4 tj;
        tj[0] = fmaxf(fmaf(agg[0], nd, bb[0]), 0.f);
        tj[1] = fmaxf(fmaf(agg[1], nd, bb[1]), 0.f);
        tj[2] = fmaxf(fmaf(agg[2], nd, bb[2]), 0.f);
        tj[3] = fmaxf(fmaf(agg[3], nd, bb[3]), 0.f);
        ((f4*)st[wid])[j4] = tj;
    }
    __builtin_amdgcn_wave_barrier();
    float r = 0.f;
    if (lane < NO) {
#pragma unroll
        for (int qq = 0; qq < NH; ++qq)
            r = fmaf(st[wid][qq], W2[qq * NO + lane], r);
    }
    if (lane < 8) {
        float ns = rsqrtf((float)max(deg_out[d], 1));
        g[(size_t)d * 8 + lane] = (lane < NO) ? ns * r : 0.f;
    }
}

// ---------------- K5: layer2 ----------------
__global__ __launch_bounds__(256)
void k_layer2(const float* __restrict__ g, const int* __restrict__ adj,
              const int* __restrict__ cnt, const float* __restrict__ b2,
              float* __restrict__ out) {
    const int lane = threadIdx.x & 63;
    const int wid  = threadIdx.x >> 6;
    const int d    = blockIdx.x * 4 + wid;
    if (d >= N_NODES) return;
    const int o4 = lane & 1, slot = lane >> 1;
    const int start = d * SLOT;
    const int deg   = min(cnt[d], SLOT);
    const int end   = start + deg;
    f4 agg = 0.f;
    for (int p = start + slot; p < end; p += 32) {
        int s = adj[p];
        agg += ((const f4*)g)[s * 2 + o4];
    }
#pragma unroll
    for (int off = 2; off < 64; off <<= 1) {
        agg[0] += __shfl_xor(agg[0], off);
        agg[1] += __shfl_xor(agg[1], off);
        agg[2] += __shfl_xor(agg[2], off);
        agg[3] += __shfl_xor(agg[3], off);
    }
    const int sl = lane >> 2;
    float v0 = __shfl(agg[0], sl);
    float v1 = __shfl(agg[1], sl);
    float v2 = __shfl(agg[2], sl);
    float v3 = __shfl(agg[3], sl);
    int cm = lane & 3;
    float v = (cm == 0) ? v0 : (cm == 1) ? v1 : (cm == 2) ? v2 : v3;
    if (lane < NO) {
        float nd = rsqrtf((float)max(deg, 1));
        out[(size_t)d * NO + lane] = fmaf(v, nd, b2[lane]);
    }
}

extern "C" void kernel_launch(void* const* d_in, const int* in_sizes, int n_in,
                              void* d_out, int out_size, void* d_ws, size_t ws_size,
                              hipStream_t stream) {
    const float* X   = (const float*)d_in[0];
    const int*   src = (const int*)d_in[1];
    const int*   dst = (const int*)d_in[2];
    const float* W1  = (const float*)d_in[3];
    const float* b1  = (const float*)d_in[4];
    const float* W2  = (const float*)d_in[5];
    const float* b2  = (const float*)d_in[6];
    float* out = (float*)d_out;

    char* w = (char*)d_ws;
    float* hpart    = (float*)w;  w += (size_t)KSPLIT * N_NODES * NH * 4;
    float* h        = (float*)w;  w += (size_t)N_NODES * NH * 4;
    float* g        = (float*)w;  w += (size_t)N_NODES * 8 * 4;
    int*   adj      = (int*)w;    w += (size_t)N_NODES * SLOT * 4;
    int*   deg_out_a= (int*)w;    w += (size_t)N_NODES * 4;
    int*   cnt      = (int*)w;    w += (size_t)N_NODES * 4;
    int2*  ebuf     = (int2*)w;   w += (size_t)N_EDGES * 8;
    int*   sbuf     = (int*)w;    w += (size_t)N_EDGES * 4;
    int*   partial_d= (int*)w;    w += (size_t)SBLK * NBKT * 4;
    int*   partial_s= (int*)w;    w += (size_t)SBLK * NBKT * 4;
    int*   pbase_d  = (int*)w;    w += (size_t)SBLK * NBKT * 4;
    int*   pbase_s  = (int*)w;    w += (size_t)SBLK * NBKT * 4;
    int*   btot_d   = (int*)w;    w += NBKT * 4;
    int*   btot_s   = (int*)w;    w += NBKT * 4;
    int*   bbase_d  = (int*)w;    w += NBKT * 4;
    int*   bbase_s  = (int*)w;    w += NBKT * 4;
    float* pout     = (float*)w;  w += (size_t)2048 * 256 * 4;   // probe scratch

    // ---- R16 bandwidth probes (pattern isolation; outputs unused) ----
    k_probe_a<<<NRBV * KSPLIT, 256, 0, stream>>>(X, pout);
    k_probe_b<<<2048,          256, 0, stream>>>(X, pout);
    k_probe_c<<<(NTILEV * 2 + 3) / 4 + 1, 256, 0, stream>>>(X, pout);

    // ---- atomic-free graph build ----
    k_pcount   <<<SBLK, 256, 0, stream>>>(dst, partial_d);
    k_pcount   <<<SBLK, 256, 0, stream>>>(src, partial_s);
    k_colscan  <<<NBKT, 256, 0, stream>>>(partial_d, pbase_d, btot_d);
    k_colscan  <<<NBKT, 256, 0, stream>>>(partial_s, pbase_s, btot_s);
    k_basescan <<<1,    256, 0, stream>>>(btot_d, bbase_d, btot_s, bbase_s);
    k_pscatter2<<<SBLK, 256, 0, stream>>>(src, dst, pbase_d, bbase_d, ebuf);
    k_pscatter1<<<SBLK, 256, 0, stream>>>(src, pbase_s, bbase_s, sbuf);
    k_adj      <<<NBKT, 512, 0, stream>>>(ebuf, bbase_d, btot_d, adj, cnt);
    k_hist     <<<NBKT, 512, 0, stream>>>(sbuf, bbase_s, btot_s, deg_out_a);

    // ---- GCN pipeline ----
    k_gemm1 <<<NRBV * KSPLIT, 256, 0, stream>>>(X, W1, hpart);
    k_reduce<<<(N_NODES * 4 + 255) / 256, 256, 0, stream>>>(hpart, deg_out_a, h);
    k_layer1<<<(N_NODES + 3) / 4, 256, 0, stream>>>(h, adj, cnt, deg_out_a,
                                                    W2, b1, g);
    k_layer2<<<(N_NODES + 3) / 4, 256, 0, stream>>>(g, adj, cnt, b2, out);
}

// Round 17
// 415.192 us; speedup vs baseline: 4.9005x; 4.9005x over previous
//
#include <hip/hip_runtime.h>
#include <math.h>

#define N_NODES  100000
#define N_EDGES  3200000
#define K_IN     1433
#define NH       16
#define NO       7

// ---- gemm1 (R17): 256B-contiguous staging, 32-row wave-tiles, 8 k-splits ----
#define TR2      32                            // rows per wave-tile
#define NT2      (N_NODES / TR2)               // 3125 tiles (exact!)
#define NRB2     ((NT2 + 3) / 4)               // 782 blocks x 4 waves
#define KS2      8                             // k-splits
#define RW2      192                           // k's per split (3 x 64 granules)
#define SX2      68                            // X LDS row stride (floats)
#define SLOT     96

#define NBKT     256
#define BKN      391
#define SBLK     512
#define EPB      ((N_EDGES + SBLK - 1) / SBLK)

typedef float f4  __attribute__((ext_vector_type(4)));
typedef float f4u __attribute__((ext_vector_type(4), aligned(4)));

// ---------------- B1..B5: atomic-free graph build (unchanged R13) ----------
__global__ __launch_bounds__(256)
void k_pcount(const int* __restrict__ key, int* __restrict__ partial) {
    __shared__ int lh[NBKT];
    lh[threadIdx.x] = 0;
    __syncthreads();
    const int e0 = blockIdx.x * EPB;
    const int e1 = min(e0 + EPB, N_EDGES);
    for (int i = e0 + threadIdx.x; i < e1; i += 256)
        atomicAdd(&lh[key[i] / BKN], 1);
    __syncthreads();
    partial[blockIdx.x * NBKT + threadIdx.x] = lh[threadIdx.x];
}

__global__ __launch_bounds__(256)
void k_colscan(const int* __restrict__ partial, int* __restrict__ pbase,
               int* __restrict__ btot) {
    __shared__ int s[256];
    const int b = blockIdx.x, t = threadIdx.x;
    const int v0 = partial[(2 * t)     * NBKT + b];
    const int v1 = partial[(2 * t + 1) * NBKT + b];
    const int pair = v0 + v1;
    s[t] = pair;
    __syncthreads();
    for (int o = 1; o < 256; o <<= 1) {
        int u = (t >= o) ? s[t - o] : 0;
        __syncthreads();
        s[t] += u;
        __syncthreads();
    }
    const int excl = s[t] - pair;
    pbase[(2 * t)     * NBKT + b] = excl;
    pbase[(2 * t + 1) * NBKT + b] = excl + v0;
    if (t == 255) btot[b] = s[255];
}

__global__ __launch_bounds__(256)
void k_basescan(const int* __restrict__ btd, int* __restrict__ bbd,
                const int* __restrict__ bts, int* __restrict__ bbs) {
    __shared__ int s[256];
    const int t = threadIdx.x;
    int v = btd[t];
    s[t] = v;
    __syncthreads();
    for (int o = 1; o < 256; o <<= 1) {
        int u = (t >= o) ? s[t - o] : 0;
        __syncthreads();
        s[t] += u;
        __syncthreads();
    }
    bbd[t] = s[t] - v;
    __syncthreads();
    v = bts[t];
    s[t] = v;
    __syncthreads();
    for (int o = 1; o < 256; o <<= 1) {
        int u = (t >= o) ? s[t - o] : 0;
        __syncthreads();
        s[t] += u;
        __syncthreads();
    }
    bbs[t] = s[t] - v;
}

__global__ __launch_bounds__(256)
void k_pscatter2(const int* __restrict__ src, const int* __restrict__ dst,
                 const int* __restrict__ pbase, const int* __restrict__ bbase,
                 int2* __restrict__ ebuf) {
    __shared__ int lh[NBKT];
    __shared__ int lb[NBKT];
    const int t = threadIdx.x;
    lh[t] = 0;
    lb[t] = bbase[t] + pbase[blockIdx.x * NBKT + t];
    __syncthreads();
    const int e0 = blockIdx.x * EPB;
    const int e1 = min(e0 + EPB, N_EDGES);
    for (int i = e0 + t; i < e1; i += 256) {
        int sv = src[i], dv = dst[i];
        int b = dv / BKN;
        int p = lb[b] + atomicAdd(&lh[b], 1);
        ebuf[p] = make_int2(sv, dv);
    }
}

__global__ __launch_bounds__(256)
void k_pscatter1(const int* __restrict__ src, const int* __restrict__ pbase,
                 const int* __restrict__ bbase, int* __restrict__ sbuf) {
    __shared__ int lh[NBKT];
    __shared__ int lb[NBKT];
    const int t = threadIdx.x;
    lh[t] = 0;
    lb[t] = bbase[t] + pbase[blockIdx.x * NBKT + t];
    __syncthreads();
    const int e0 = blockIdx.x * EPB;
    const int e1 = min(e0 + EPB, N_EDGES);
    for (int i = e0 + t; i < e1; i += 256) {
        int sv = src[i];
        int b = sv / BKN;
        int p = lb[b] + atomicAdd(&lh[b], 1);
        sbuf[p] = sv;
    }
}

__global__ __launch_bounds__(512)
void k_adj(const int2* __restrict__ ebuf, const int* __restrict__ bbase,
           const int* __restrict__ btot, int* __restrict__ adj,
           int* __restrict__ cnt) {
    __shared__ int cur[BKN];
    const int b = blockIdx.x;
    for (int i = threadIdx.x; i < BKN; i += 512) cur[i] = 0;
    __syncthreads();
    const int s0 = bbase[b], s1 = s0 + btot[b];
    const int nb = b * BKN;
    for (int i = s0 + threadIdx.x; i < s1; i += 512) {
        int2 e = ebuf[i];
        int p = atomicAdd(&cur[e.y - nb], 1);
        if (p < SLOT) adj[e.y * SLOT + p] = e.x;
    }
    __syncthreads();
    for (int i = threadIdx.x; i < BKN; i += 512) {
        int n = nb + i;
        if (n < N_NODES) cnt[n] = cur[i];
    }
}

__global__ __launch_bounds__(512)
void k_hist(const int* __restrict__ sbuf, const int* __restrict__ bbase,
            const int* __restrict__ btot, int* __restrict__ deg) {
    __shared__ int cur[BKN];
    const int b = blockIdx.x;
    for (int i = threadIdx.x; i < BKN; i += 512) cur[i] = 0;
    __syncthreads();
    const int s0 = bbase[b], s1 = s0 + btot[b];
    const int nb = b * BKN;
    for (int i = s0 + threadIdx.x; i < s1; i += 512)
        atomicAdd(&cur[sbuf[i] - nb], 1);
    __syncthreads();
    for (int i = threadIdx.x; i < BKN; i += 512) {
        int n = nb + i;
        if (n < N_NODES) deg[n] = cur[i];
    }
}

// ---------------- K2: hpart[split] = X[:, ksplit] @ W1[ksplit, :] ----------
// R16 probes: 64B/row staging = 3.5 TB/s (probe_a); 256B-contiguous/row =
// >5.5 TB/s (probe_c). New staging: granule = 64 k's; each load instr = 4
// rows x 256B contiguous (16 lanes x 16B). Straight-line 3-granule schedule,
// named P/Q sets. Compute: j-split, W via 16-way-broadcast ds_read_b128.

#define LOADX_FULL(KO, S0,S1,S2,S3,S4,S5,S6,S7)                      \
  { S0 = *(const f4u*)(xrow + 0*4*K_IN + (KO));                      \
    S1 = *(const f4u*)(xrow + 1*4*K_IN + (KO));                      \
    S2 = *(const f4u*)(xrow + 2*4*K_IN + (KO));                      \
    S3 = *(const f4u*)(xrow + 3*4*K_IN + (KO));                      \
    S4 = *(const f4u*)(xrow + 4*4*K_IN + (KO));                      \
    S5 = *(const f4u*)(xrow + 5*4*K_IN + (KO));                      \
    S6 = *(const f4u*)(xrow + 6*4*K_IN + (KO));                      \
    S7 = *(const f4u*)(xrow + 7*4*K_IN + (KO)); }

#define LOADX_TAIL(KO, S0,S1,S2,S3,S4,S5,S6,S7)                      \
  { S0=0.f;S1=0.f;S2=0.f;S3=0.f;S4=0.f;S5=0.f;S6=0.f;S7=0.f;         \
    const int kl_ = (KO) + 4 * Lq;                                   \
    if (kl_ + 3 < K_IN) {                                            \
      LOADX_FULL(KO, S0,S1,S2,S3,S4,S5,S6,S7)                        \
    } else {                                                         \
      _Pragma("unroll")                                              \
      for (int m_ = 0; m_ < 4; ++m_)                                 \
        if (kl_ + m_ < K_IN) {                                       \
          S0[m_] = xrow[0*4*K_IN + (KO) + m_];                       \
          S1[m_] = xrow[1*4*K_IN + (KO) + m_];                       \
          S2[m_] = xrow[2*4*K_IN + (KO) + m_];                       \
          S3[m_] = xrow[3*4*K_IN + (KO) + m_];                       \
          S4[m_] = xrow[4*4*K_IN + (KO) + m_];                       \
          S5[m_] = xrow[5*4*K_IN + (KO) + m_];                       \
          S6[m_] = xrow[6*4*K_IN + (KO) + m_];                       \
          S7[m_] = xrow[7*4*K_IN + (KO) + m_];                       \
        }                                                            \
    } }

#define LOADX(KO, S0,S1,S2,S3,S4,S5,S6,S7)                           \
  { if ((KO) + 64 <= K_IN) { LOADX_FULL(KO, S0,S1,S2,S3,S4,S5,S6,S7) } \
    else                   { LOADX_TAIL(KO, S0,S1,S2,S3,S4,S5,S6,S7) } }

// write 8 granule-rows (rows Lr+4i, cols 4Lq..4Lq+3)
#define WRX(S0,S1,S2,S3,S4,S5,S6,S7)                                 \
  { *(f4*)(xbw + 0*4*SX2) = S0; *(f4*)(xbw + 1*4*SX2) = S1;          \
    *(f4*)(xbw + 2*4*SX2) = S2; *(f4*)(xbw + 3*4*SX2) = S3;          \
    *(f4*)(xbw + 4*4*SX2) = S4; *(f4*)(xbw + 5*4*SX2) = S5;          \
    *(f4*)(xbw + 6*4*SX2) = S6; *(f4*)(xbw + 7*4*SX2) = S7; }

// compute 64 k's of granule (W slice row offset GOFF); rows rg, rg+16
#define CFMA(GOFF)                                                   \
  { const float* wb = wjq + (GOFF) * NH;                             \
    _Pragma("unroll")                                                \
    for (int kq = 0; kq < 16; ++kq) {                                \
      f4 xA = *(const f4*)(xrdA + kq * 4);                           \
      f4 xB = *(const f4*)(xrdB + kq * 4);                           \
      f4 w0 = *(const f4*)(wb + (kq*4+0) * NH);                      \
      f4 w1 = *(const f4*)(wb + (kq*4+1) * NH);                      \
      f4 w2 = *(const f4*)(wb + (kq*4+2) * NH);                      \
      f4 w3 = *(const f4*)(wb + (kq*4+3) * NH);                      \
      acc0 += xA[0]*w0; acc0 += xA[1]*w1;                            \
      acc0 += xA[2]*w2; acc0 += xA[3]*w3;                            \
      acc1 += xB[0]*w0; acc1 += xB[1]*w1;                            \
      acc1 += xB[2]*w2; acc1 += xB[3]*w3;                            \
    } }

__global__ __launch_bounds__(256)
void k_gemm1(const float* __restrict__ X, const float* __restrict__ W1,
             float* __restrict__ hpart) {
    __shared__ float wlds[RW2 * NH];               // 12288 B
    __shared__ float sX[4][TR2 * SX2];             // 4 x 8704 B
    const int wid = threadIdx.x >> 6;
    const int t   = threadIdx.x & 63;
    const int rb    = blockIdx.x % NRB2;
    const int split = blockIdx.x / NRB2;

    // stage this split's W1 slice (768 f4 = 3 x 256; zero past K_IN)
    {
        const f4* W1v = (const f4*)W1;
        const int wbase = split * RW2;
#pragma unroll
        for (int r = 0; r < 3; ++r) {
            int idx = r * 256 + threadIdx.x;       // 0..767
            int krow = wbase + (idx >> 2);
            f4 wv = 0.f;
            if (krow < K_IN) wv = W1v[krow * 4 + (idx & 3)];
            ((f4*)wlds)[idx] = wv;
        }
    }
    __syncthreads();

    const int tile = rb * 4 + wid;
    if (tile >= NT2) return;                       // wave-uniform, after sync
    const int base = tile * TR2;                   // rows exact (100000%32==0)
    const int Lq = t & 15;                         // 16B slice within 256B span
    const int Lr = t >> 4;                         // staging row 0..3
    const int rg = t >> 2;                         // compute row-group 0..15
    const int jq = t & 3;                          // compute j-quad

    const float* xrow = X + (size_t)(base + Lr) * K_IN + 4 * Lq;

    float* xbuf = sX[wid];
    float* xbw  = xbuf + Lr * SX2 + 4 * Lq;        // stage write base
    const float* xrdA = xbuf + rg * SX2;           // compute row rg
    const float* xrdB = xbuf + (rg + 16) * SX2;    // compute row rg+16
    const float* wjq  = wlds + jq * 4;             // own j-quad

    f4 acc0 = 0.f, acc1 = 0.f;
    f4 P0, P1, P2, P3, P4, P5, P6, P7;
    f4 Q0, Q1, Q2, Q3, Q4, Q5, Q6, Q7;

    const int kb = split * RW2;

    LOADX(kb +   0, P0, P1, P2, P3, P4, P5, P6, P7)      // g0
    WRX(P0, P1, P2, P3, P4, P5, P6, P7)
    LOADX(kb +  64, Q0, Q1, Q2, Q3, Q4, Q5, Q6, Q7)      // prefetch g1
    __builtin_amdgcn_wave_barrier();
    CFMA(0)
    __builtin_amdgcn_wave_barrier();
    WRX(Q0, Q1, Q2, Q3, Q4, Q5, Q6, Q7)
    LOADX(kb + 128, P0, P1, P2, P3, P4, P5, P6, P7)      // prefetch g2
    __builtin_amdgcn_wave_barrier();
    CFMA(64)
    __builtin_amdgcn_wave_barrier();
    WRX(P0, P1, P2, P3, P4, P5, P6, P7)
    __builtin_amdgcn_wave_barrier();
    CFMA(128)

    // coalesced store: lane (rg,jq) -> contiguous 1KB per wave
    const size_t sb = (size_t)split * N_NODES;
    float* op = hpart + (sb + base + rg) * NH + jq * 4;
    *(f4*)op = acc0;
    *(f4*)(op + (size_t)16 * NH) = acc1;
}

// ---------------- K3: h = norm_src * sum_s hpart[s] ----------------
__global__ __launch_bounds__(256)
void k_reduce(const float* __restrict__ hpart, const int* __restrict__ deg_out,
              float* __restrict__ h) {
    int idx = blockIdx.x * 256 + threadIdx.x;   // f4 index
    if (idx >= N_NODES * 4) return;
    f4 a = 0.f;
#pragma unroll
    for (int s = 0; s < KS2; ++s)
        a += ((const f4*)hpart)[(size_t)s * N_NODES * 4 + idx];
    float ns = rsqrtf((float)max(deg_out[idx >> 2], 1));
    ((f4*)h)[idx] = a * ns;
}

// ---------------- K4: gather layer1 + relu + fused (.. @ W2) ----------------
__global__ __launch_bounds__(256)
void k_layer1(const float* __restrict__ h, const int* __restrict__ adj,
              const int* __restrict__ cnt, const int* __restrict__ deg_out,
              const float* __restrict__ W2, const float* __restrict__ b1,
              float* __restrict__ g) {
    const int lane = threadIdx.x & 63;
    const int wid  = threadIdx.x >> 6;
    const int d    = blockIdx.x * 4 + wid;
    if (d >= N_NODES) return;
    const int j4 = lane & 3, slot = lane >> 2;
    const int start = d * SLOT;
    const int deg   = min(cnt[d], SLOT);
    const int end   = start + deg;
    f4 agg = 0.f;
    for (int p = start + slot; p < end; p += 16) {
        int s = adj[p];
        agg += ((const f4*)h)[s * 4 + j4];
    }
#pragma unroll
    for (int off = 4; off < 64; off <<= 1) {
        agg[0] += __shfl_xor(agg[0], off);
        agg[1] += __shfl_xor(agg[1], off);
        agg[2] += __shfl_xor(agg[2], off);
        agg[3] += __shfl_xor(agg[3], off);
    }
    __shared__ float st[4][NH];
    const float nd = rsqrtf((float)max(deg, 1));
    if (slot == 0) {
        f4 bb = ((const f4*)b1)[j4];
        f4 tj;
        tj[0] = fmaxf(fmaf(agg[0], nd, bb[0]), 0.f);
        tj[1] = fmaxf(fmaf(agg[1], nd, bb[1]), 0.f);
        tj[2] = fmaxf(fmaf(agg[2], nd, bb[2]), 0.f);
        tj[3] = fmaxf(fmaf(agg[3], nd, bb[3]), 0.f);
        ((f4*)st[wid])[j4] = tj;
    }
    __builtin_amdgcn_wave_barrier();
    float r = 0.f;
    if (lane < NO) {
#pragma unroll
        for (int qq = 0; qq < NH; ++qq)
            r = fmaf(st[wid][qq], W2[qq * NO + lane], r);
    }
    if (lane < 8) {
        float ns = rsqrtf((float)max(deg_out[d], 1));
        g[(size_t)d * 8 + lane] = (lane < NO) ? ns * r : 0.f;
    }
}

// ---------------- K5: gather layer2 -> out ----------------
__global__ __launch_bounds__(256)
void k_layer2(const float* __restrict__ g, const int* __restrict__ adj,
              const int* __restrict__ cnt, const float* __restrict__ b2,
              float* __restrict__ out) {
    const int lane = threadIdx.x & 63;
    const int wid  = threadIdx.x >> 6;
    const int d    = blockIdx.x * 4 + wid;
    if (d >= N_NODES) return;
    const int o4 = lane & 1, slot = lane >> 1;
    const int start = d * SLOT;
    const int deg   = min(cnt[d], SLOT);
    const int end   = start + deg;
    f4 agg = 0.f;
    for (int p = start + slot; p < end; p += 32) {
        int s = adj[p];
        agg += ((const f4*)g)[s * 2 + o4];
    }
#pragma unroll
    for (int off = 2; off < 64; off <<= 1) {
        agg[0] += __shfl_xor(agg[0], off);
        agg[1] += __shfl_xor(agg[1], off);
        agg[2] += __shfl_xor(agg[2], off);
        agg[3] += __shfl_xor(agg[3], off);
    }
    const int sl = lane >> 2;
    float v0 = __shfl(agg[0], sl);
    float v1 = __shfl(agg[1], sl);
    float v2 = __shfl(agg[2], sl);
    float v3 = __shfl(agg[3], sl);
    int cm = lane & 3;
    float v = (cm == 0) ? v0 : (cm == 1) ? v1 : (cm == 2) ? v2 : v3;
    if (lane < NO) {
        float nd = rsqrtf((float)max(deg, 1));
        out[(size_t)d * NO + lane] = fmaf(v, nd, b2[lane]);
    }
}

extern "C" void kernel_launch(void* const* d_in, const int* in_sizes, int n_in,
                              void* d_out, int out_size, void* d_ws, size_t ws_size,
                              hipStream_t stream) {
    const float* X   = (const float*)d_in[0];
    const int*   src = (const int*)d_in[1];
    const int*   dst = (const int*)d_in[2];
    const float* W1  = (const float*)d_in[3];
    const float* b1  = (const float*)d_in[4];
    const float* W2  = (const float*)d_in[5];
    const float* b2  = (const float*)d_in[6];
    float* out = (float*)d_out;

    char* w = (char*)d_ws;
    float* hpart    = (float*)w;  w += (size_t)KS2 * N_NODES * NH * 4;    // 51.2 MB
    float* h        = (float*)w;  w += (size_t)N_NODES * NH * 4;          // 6.4 MB
    float* g        = (float*)w;  w += (size_t)N_NODES * 8 * 4;           // 3.2 MB
    int*   adj      = (int*)w;    w += (size_t)N_NODES * SLOT * 4;        // 38.4 MB
    int*   deg_out_a= (int*)w;    w += (size_t)N_NODES * 4;
    int*   cnt      = (int*)w;    w += (size_t)N_NODES * 4;
    int2*  ebuf     = (int2*)w;   w += (size_t)N_EDGES * 8;               // 25.6 MB
    int*   sbuf     = (int*)w;    w += (size_t)N_EDGES * 4;               // 12.8 MB
    int*   partial_d= (int*)w;    w += (size_t)SBLK * NBKT * 4;
    int*   partial_s= (int*)w;    w += (size_t)SBLK * NBKT * 4;
    int*   pbase_d  = (int*)w;    w += (size_t)SBLK * NBKT * 4;
    int*   pbase_s  = (int*)w;    w += (size_t)SBLK * NBKT * 4;
    int*   btot_d   = (int*)w;    w += NBKT * 4;
    int*   btot_s   = (int*)w;    w += NBKT * 4;
    int*   bbase_d  = (int*)w;    w += NBKT * 4;
    int*   bbase_s  = (int*)w;    w += NBKT * 4;

    // ---- atomic-free graph build (counting sort by 391-node buckets) ----
    k_pcount   <<<SBLK, 256, 0, stream>>>(dst, partial_d);
    k_pcount   <<<SBLK, 256, 0, stream>>>(src, partial_s);
    k_colscan  <<<NBKT, 256, 0, stream>>>(partial_d, pbase_d, btot_d);
    k_colscan  <<<NBKT, 256, 0, stream>>>(partial_s, pbase_s, btot_s);
    k_basescan <<<1,    256, 0, stream>>>(btot_d, bbase_d, btot_s, bbase_s);
    k_pscatter2<<<SBLK, 256, 0, stream>>>(src, dst, pbase_d, bbase_d, ebuf);
    k_pscatter1<<<SBLK, 256, 0, stream>>>(src, pbase_s, bbase_s, sbuf);
    k_adj      <<<NBKT, 512, 0, stream>>>(ebuf, bbase_d, btot_d, adj, cnt);
    k_hist     <<<NBKT, 512, 0, stream>>>(sbuf, bbase_s, btot_s, deg_out_a);

    // ---- GCN pipeline ----
    k_gemm1 <<<NRB2 * KS2, 256, 0, stream>>>(X, W1, hpart);
    k_reduce<<<(N_NODES * 4 + 255) / 256, 256, 0, stream>>>(hpart, deg_out_a, h);
    k_layer1<<<(N_NODES + 3) / 4, 256, 0, stream>>>(h, adj, cnt, deg_out_a,
                                                    W2, b1, g);
    k_layer2<<<(N_NODES + 3) / 4, 256, 0, stream>>>(g, adj, cnt, b2, out);
}